// Round 1
// baseline (186.296 us; speedup 1.0000x reference)
//
#include <hip/hip_runtime.h>
#include <math.h>

// Problem constants (from reference setup_inputs)
#define BBATCH 16
#define NPTS   4096
#define MPTS   1024
#define C1c    128
#define C2c    256
#define CINc   384
#define H1c    256
#define H2c    128
#define TN     64

typedef _Float16 f16x8 __attribute__((ext_vector_type(8)));
typedef _Float16 f16x4 __attribute__((ext_vector_type(4)));
typedef float    f32x4 __attribute__((ext_vector_type(4)));

// ---- LDS: fragment-contiguous union + reduction scratch -------------------
// phase A: inv dbuf  2 x [4 cc][4 nt][64 lane][8 f16] = 2 x 16384 B
// phase B: s_X frags [8 kc'][4 nt][64][8] f16 = 32768 B   (kc' = c/32, interp only)
// phase C: s_H frags [8 oc][4 nt][64][8] f16 = 32768 B
// + s_red 256 f32 (block reduction; recip overlaid into first 64 entries)
// Total 33792 B -> 4 blocks/CU (was 52736 B -> 3 blocks/CU + serial tail).
#define INV_HALF   8192            // f16 elems per inv buffer (16384 B)
#define SMEM_UNION 32768
#define SMEM_BYTES (SMEM_UNION + 1024)

// ---- fragment-swizzled workspace layout (f16 elements), unchanged ----
//   p2s: frag ((b*32+s)*16 + wt)*64 + lane : (c=wt*16+(lane&15), m=s*32+(lane>>4)*8+i)
//   W1s: frag (wt*12 + kc)*64 + lane       : (o=wt*16+(lane&15), k=kc*32+(lane>>4)*8+i)
//   W2s: frag (wt2*8 + oc)*64 + lane       : (o=wt2*16+(lane&15), k=oc*32+(lane>>4)*8+i)
#define NFRAG_P2  (BBATCH * 32 * 16 * 64)        // 524288
#define NFRAG_W1  (16 * 12 * 64)                 // 12288
#define NFRAG_W2  (8 * 8 * 64)                   // 4096
#define WS_P2S  0
#define WS_W1S  (NFRAG_P2 * 8)                   // 4194304
#define WS_W2S  (WS_W1S + NFRAG_W1 * 8)
#define WS_F16_TOTAL (WS_W2S + NFRAG_W2 * 8)     // 4325376 f16 = 8650752 B

// ---------------------------------------------------------------------------
// pre-pass: convert + swizzle p2 / W1 / W2 into fragment-contiguous f16
__global__ __launch_bounds__(256) void cvt_swz(
    const float* __restrict__ p2, const float* __restrict__ W1,
    const float* __restrict__ W2, _Float16* __restrict__ ws)
{
    const int t = blockIdx.x * 256 + threadIdx.x;   // one fragment (8 f16) per thread
    const float* src;
    _Float16* dst;
    if (t < NFRAG_P2) {
        const int lane = t & 63, wt = (t >> 6) & 15, s = (t >> 10) & 31, b = t >> 15;
        const int c = wt * 16 + (lane & 15);
        const int m = s * 32 + (lane >> 4) * 8;
        src = p2 + ((size_t)(b * C2c + c)) * MPTS + m;
        dst = ws + WS_P2S + (size_t)t * 8;
    } else if (t < NFRAG_P2 + NFRAG_W1) {
        const int u = t - NFRAG_P2;
        const int lane = u & 63, kc = (u >> 6) % 12, wt = (u >> 6) / 12;
        const int o = wt * 16 + (lane & 15);
        const int k = kc * 32 + (lane >> 4) * 8;
        src = W1 + (size_t)o * CINc + k;
        dst = ws + WS_W1S + (size_t)u * 8;
    } else {
        const int v = t - NFRAG_P2 - NFRAG_W1;
        const int lane = v & 63, oc = (v >> 6) & 7, wt2 = v >> 9;
        const int o = wt2 * 16 + (lane & 15);
        const int k = oc * 32 + (lane >> 4) * 8;
        src = W2 + (size_t)o * H1c + k;
        dst = ws + WS_W2S + (size_t)v * 8;
    }
    const float4 a0 = *(const float4*)(src);
    const float4 a1 = *(const float4*)(src + 4);
    f16x8 h;
    h[0] = (_Float16)a0.x; h[1] = (_Float16)a0.y; h[2] = (_Float16)a0.z; h[3] = (_Float16)a0.w;
    h[4] = (_Float16)a1.x; h[5] = (_Float16)a1.y; h[6] = (_Float16)a1.z; h[7] = (_Float16)a1.w;
    *(f16x8*)dst = h;
}

// ---------------------------------------------------------------------------
// R8: 4-blocks/CU residency + fragment-contiguous LDS everywhere.
//  - xyz2 read direct from global (wave-uniform, L2-resident; each slice read
//    once per block -> LDS staging was pure overhead).
//  - inv super-chunk buffers in B-frag layout: gen() writes one f16x8 per
//    thread per g, dense & conflict-free; phase-A B-reads are contiguous
//    1 KB/wave ds_read_b128.
//  - s_X holds ONLY the interpolated features (k=128..383) as frags; the p1
//    half of phase-B K is gathered per-lane from global (L1/L2-resident tile).
//  - s_H in frag layout. All barriers/dataflow otherwise as R7.
template <bool F16P>
__global__ __launch_bounds__(256, 4) void fp_mfma8(
    const float* __restrict__ xyz1, const float* __restrict__ xyz2,
    const float* __restrict__ p1,   const float* __restrict__ p2,
    const float* __restrict__ W1,   const float* __restrict__ b1v,
    const float* __restrict__ W2,   const float* __restrict__ b2v,
    const _Float16* __restrict__ p2s, const _Float16* __restrict__ W1s,
    const _Float16* __restrict__ W2s,
    float* __restrict__ out)
{
    __shared__ __align__(16) char smem[SMEM_BYTES];
    _Float16* s_inv = (_Float16*)smem;
    _Float16* s_X   = (_Float16*)smem;
    _Float16* s_H   = (_Float16*)smem;
    float*    s_red = (float*)(smem + SMEM_UNION);

    const int tid  = threadIdx.x;
    const int w    = tid >> 6;    // wave 0..3
    const int L    = tid & 63;
    const int quad = L >> 4;
    const int l16  = L & 15;

    // XCD swizzle: each XCD sees 2 batches -> p2s working set (1 MB) L2-resident
    const int id = blockIdx.x;
    const int b  = (id & 7) * 2 + ((id >> 3) & 1);
    const int n0 = (id >> 4) * TN;

    const float* __restrict__ z2b = xyz2 + (size_t)b * MPTS * 3;
    const float* __restrict__ p2b = p2   + (size_t)b * C2c * MPTS;
    const _Float16* __restrict__ p2sb =
        F16P ? (p2s + (((size_t)b * 32 * 16 + (size_t)w * 4) * 64 + L) * 8) : (const _Float16*)nullptr;

    const float x1x = xyz1[((size_t)b * NPTS + n0 + L) * 3 + 0];
    const float x1y = xyz1[((size_t)b * NPTS + n0 + L) * 3 + 1];
    const float x1z = xyz1[((size_t)b * NPTS + n0 + L) * 3 + 2];

    f32x4 acc[4][4];   // [ct][nt]: row c = w*64+ct*16+quad*4+r, col n = nt*16+l16
    #pragma unroll
    for (int ct = 0; ct < 4; ++ct)
        #pragma unroll
        for (int nt = 0; nt < 4; ++nt)
            acc[ct][nt] = (f32x4){0.f, 0.f, 0.f, 0.f};

    float ssum = 0.f;
    f16x8 Aa[2][4];    // A-frag register dbuf, parity = chunk index & 1

    auto loadA = [&](int s, f16x8 dst[4]) {
        if (F16P) {
            const _Float16* ap = p2sb + (size_t)s * (16 * 64 * 8);
            #pragma unroll
            for (int ct = 0; ct < 4; ++ct)
                dst[ct] = *(const f16x8*)(ap + (size_t)ct * (64 * 8));
        } else {
            const float* ap = p2b + (size_t)(w * 64 + l16) * MPTS + s * 32 + quad * 8;
            #pragma unroll
            for (int ct = 0; ct < 4; ++ct) {
                const float4 a0 = *(const float4*)(ap + (size_t)ct * (16 * MPTS));
                const float4 a1 = *(const float4*)(ap + (size_t)ct * (16 * MPTS) + 4);
                f16x8 h;
                h[0] = (_Float16)a0.x; h[1] = (_Float16)a0.y; h[2] = (_Float16)a0.z; h[3] = (_Float16)a0.w;
                h[4] = (_Float16)a1.x; h[5] = (_Float16)a1.y; h[6] = (_Float16)a1.z; h[7] = (_Float16)a1.w;
                dst[ct] = h;
            }
        }
    };

    // generate the 128-m super-chunk ss into frag-layout buffer (ss&1).
    // thread (w,L): n=L, m = ss*128 + w*32 + g*8 + i  ->  frag (cc=w, nt=quad),
    // lane slot l' = 16*g + l16, elems j=i. One dense f16x8 store per g.
    auto gen = [&](int ss_) {
        _Float16* buf = s_inv + (ss_ & 1) * INV_HALF;
        const float* zbase = z2b + (size_t)(ss_ * 128 + w * 32) * 3;   // wave-uniform, 16B-aligned
        #pragma unroll
        for (int g = 0; g < 4; ++g) {
            const float* zp = zbase + g * 24;
            f32x4 zr[6];
            #pragma unroll
            for (int j = 0; j < 6; ++j) zr[j] = ((const f32x4*)zp)[j];
            const float* zv = (const float*)zr;
            f16x8 iv;
            #pragma unroll
            for (int i = 0; i < 8; ++i) {
                const float dx = x1x - zv[3 * i + 0];
                const float dy = x1y - zv[3 * i + 1];
                const float dz = x1z - zv[3 * i + 2];
                const float d2 = fmaf(dx, dx, fmaf(dy, dy, fmaf(dz, dz, 1e-12f)));
                const float inv = __builtin_amdgcn_rsqf(d2);
                ssum += inv;
                iv[i] = (_Float16)inv;
            }
            *(f16x8*)(buf + (((w * 4 + quad) * 64) + g * 16 + l16) * 8) = iv;
        }
    };

    loadA(0, Aa[0]);
    gen(0);
    __syncthreads();   // super-chunk 0 visible

    for (int ss = 0; ss < 8; ++ss) {
        if (ss + 1 < 8) gen(ss + 1);   // fills other buffer; overlaps inner MFMAs
        const _Float16* buf = s_inv + (ss & 1) * INV_HALF;
        #pragma unroll
        for (int cc = 0; cc < 4; ++cc) {
            const int s = ss * 4 + cc;
            if (s + 1 < 32) loadA(s + 1, Aa[(cc + 1) & 1]);   // barrier-free prefetch
            #pragma unroll
            for (int nt = 0; nt < 4; ++nt) {
                const f16x8 bf = *(const f16x8*)(buf + ((cc * 4 + nt) * 64 + L) * 8);
                #pragma unroll
                for (int ct = 0; ct < 4; ++ct)
                    acc[ct][nt] = __builtin_amdgcn_mfma_f32_16x16x32_f16(Aa[cc & 1][ct], bf, acc[ct][nt], 0, 0, 0);
            }
        }
        __syncthreads();   // reads of buf(ss) done; writes of buf(ss+1) done
    }

    // ---- S[n] reduction over the 4 m-slice partials; recip overlaid in s_red
    s_red[tid] = ssum;
    __syncthreads();
    if (tid < 64)
        s_red[tid] = 1.0f / (s_red[tid] + s_red[tid + 64] + s_red[tid + 128] + s_red[tid + 192]);
    __syncthreads();   // recip ready; phase-A scratch dead -> s_X overlay safe

    // interp -> s_X frag layout: value (n = nt*16+l16, c = w*64+ct*16+quad*4+r)
    //   frag kc' = 2w + (ct>>1), lane slot = l16 + 16*((ct&1)*2 + (quad>>1)),
    //   elem offset (quad&1)*4 + r  -> one dense f16x4 store per (ct,nt).
    {
        float rn4[4];
        #pragma unroll
        for (int nt = 0; nt < 4; ++nt) rn4[nt] = s_red[nt * 16 + l16];
        #pragma unroll
        for (int ct = 0; ct < 4; ++ct) {
            const int kq = 2 * w + (ct >> 1);
            const int lp = l16 + 16 * (((ct & 1) * 2) + (quad >> 1));
            const int jo = (quad & 1) * 4;
            #pragma unroll
            for (int nt = 0; nt < 4; ++nt) {
                const f32x4 v = acc[ct][nt];
                const float r = rn4[nt];
                f16x4 hv;
                hv[0] = (_Float16)(v[0] * r);
                hv[1] = (_Float16)(v[1] * r);
                hv[2] = (_Float16)(v[2] * r);
                hv[3] = (_Float16)(v[3] * r);
                *(f16x4*)(s_X + ((kq * 4 + nt) * 64 + lp) * 8 + jo) = hv;
            }
        }
    }
    __syncthreads();   // interp frags complete

    // ---------------- Phase B: h = relu(W1 @ [p1; U] + b1), K=384 ----------
    f32x4 hacc[4][4];
    #pragma unroll
    for (int ct = 0; ct < 4; ++ct)
        #pragma unroll
        for (int nt = 0; nt < 4; ++nt)
            hacc[ct][nt] = (f32x4){0.f, 0.f, 0.f, 0.f};

    // kc 0..3: B-frag gathered per-lane from p1 (tile is L1/L2-resident).
    // lane L holds k = kc*32 + quad*8 + j, n = n0 + nt*16 + l16.
    {
        const float* p1f = p1 + ((size_t)b * C1c + quad * 8) * NPTS + n0 + l16;
        #pragma unroll
        for (int kc = 0; kc < 4; ++kc) {
            f16x8 af[4];
            if (F16P) {
                const _Float16* wp = W1s + (((size_t)(w * 4) * 12 + kc) * 64 + L) * 8;
                #pragma unroll
                for (int ct = 0; ct < 4; ++ct)
                    af[ct] = *(const f16x8*)(wp + (size_t)ct * (12 * 64 * 8));
            } else {
                const float* wp = W1 + (size_t)(w * 64 + l16) * CINc + kc * 32 + quad * 8;
                #pragma unroll
                for (int ct = 0; ct < 4; ++ct) {
                    const float4 a0 = *(const float4*)(wp + ct * (16 * CINc));
                    const float4 a1 = *(const float4*)(wp + ct * (16 * CINc) + 4);
                    f16x8 h;
                    h[0] = (_Float16)a0.x; h[1] = (_Float16)a0.y; h[2] = (_Float16)a0.z; h[3] = (_Float16)a0.w;
                    h[4] = (_Float16)a1.x; h[5] = (_Float16)a1.y; h[6] = (_Float16)a1.z; h[7] = (_Float16)a1.w;
                    af[ct] = h;
                }
            }
            #pragma unroll
            for (int nt = 0; nt < 4; ++nt) {
                const float* pp = p1f + (size_t)(kc * 32) * NPTS + nt * 16;
                float t[8];
                #pragma unroll
                for (int j = 0; j < 8; ++j) t[j] = pp[(size_t)j * NPTS];
                f16x8 bf;
                #pragma unroll
                for (int j = 0; j < 8; ++j) bf[j] = (_Float16)t[j];
                #pragma unroll
                for (int ct = 0; ct < 4; ++ct)
                    hacc[ct][nt] = __builtin_amdgcn_mfma_f32_16x16x32_f16(af[ct], bf, hacc[ct][nt], 0, 0, 0);
            }
        }
    }

    // kc 4..11: B-frags contiguous from s_X
    #pragma unroll 2
    for (int kc = 4; kc < 12; ++kc) {
        f16x8 af[4];
        if (F16P) {
            const _Float16* wp = W1s + (((size_t)(w * 4) * 12 + kc) * 64 + L) * 8;
            #pragma unroll
            for (int ct = 0; ct < 4; ++ct)
                af[ct] = *(const f16x8*)(wp + (size_t)ct * (12 * 64 * 8));
        } else {
            const float* wp = W1 + (size_t)(w * 64 + l16) * CINc + kc * 32 + quad * 8;
            #pragma unroll
            for (int ct = 0; ct < 4; ++ct) {
                const float4 a0 = *(const float4*)(wp + ct * (16 * CINc));
                const float4 a1 = *(const float4*)(wp + ct * (16 * CINc) + 4);
                f16x8 h;
                h[0] = (_Float16)a0.x; h[1] = (_Float16)a0.y; h[2] = (_Float16)a0.z; h[3] = (_Float16)a0.w;
                h[4] = (_Float16)a1.x; h[5] = (_Float16)a1.y; h[6] = (_Float16)a1.z; h[7] = (_Float16)a1.w;
                af[ct] = h;
            }
        }
        #pragma unroll
        for (int nt = 0; nt < 4; ++nt) {
            const f16x8 bf = *(const f16x8*)(s_X + (((kc - 4) * 4 + nt) * 64 + L) * 8);
            #pragma unroll
            for (int ct = 0; ct < 4; ++ct)
                hacc[ct][nt] = __builtin_amdgcn_mfma_f32_16x16x32_f16(af[ct], bf, hacc[ct][nt], 0, 0, 0);
        }
    }

    __syncthreads();   // all s_X reads done before overlaying s_H

    // bias + relu + stage h -> s_H frag layout (same mapping as interp, oc=2w+(ct>>1))
    {
        f32x4 bb[4];
        #pragma unroll
        for (int ct = 0; ct < 4; ++ct)
            bb[ct] = *(const f32x4*)(b1v + w * 64 + ct * 16 + quad * 4);
        #pragma unroll
        for (int ct = 0; ct < 4; ++ct) {
            const int oq = 2 * w + (ct >> 1);
            const int lp = l16 + 16 * (((ct & 1) * 2) + (quad >> 1));
            const int jo = (quad & 1) * 4;
            #pragma unroll
            for (int nt = 0; nt < 4; ++nt) {
                const f32x4 v = hacc[ct][nt];
                f16x4 hv;
                hv[0] = (_Float16)fmaxf(v[0] + bb[ct][0], 0.f);
                hv[1] = (_Float16)fmaxf(v[1] + bb[ct][1], 0.f);
                hv[2] = (_Float16)fmaxf(v[2] + bb[ct][2], 0.f);
                hv[3] = (_Float16)fmaxf(v[3] + bb[ct][3], 0.f);
                *(f16x4*)(s_H + ((oq * 4 + nt) * 64 + lp) * 8 + jo) = hv;
            }
        }
    }
    __syncthreads();

    // ---------------- Phase C: out = relu(W2 @ h + b2), K=256 --------------
    f32x4 oacc[2][4];
    #pragma unroll
    for (int ct = 0; ct < 2; ++ct)
        #pragma unroll
        for (int nt = 0; nt < 4; ++nt)
            oacc[ct][nt] = (f32x4){0.f, 0.f, 0.f, 0.f};

    #pragma unroll 2
    for (int oc = 0; oc < 8; ++oc) {
        f16x8 af2[2];
        if (F16P) {
            const _Float16* wp = W2s + (((size_t)(w * 2) * 8 + oc) * 64 + L) * 8;
            #pragma unroll
            for (int ct = 0; ct < 2; ++ct)
                af2[ct] = *(const f16x8*)(wp + (size_t)ct * (8 * 64 * 8));
        } else {
            const float* wp = W2 + (size_t)(w * 32 + l16) * H1c + oc * 32 + quad * 8;
            #pragma unroll
            for (int ct = 0; ct < 2; ++ct) {
                const float4 a0 = *(const float4*)(wp + ct * (16 * H1c));
                const float4 a1 = *(const float4*)(wp + ct * (16 * H1c) + 4);
                f16x8 h;
                h[0] = (_Float16)a0.x; h[1] = (_Float16)a0.y; h[2] = (_Float16)a0.z; h[3] = (_Float16)a0.w;
                h[4] = (_Float16)a1.x; h[5] = (_Float16)a1.y; h[6] = (_Float16)a1.z; h[7] = (_Float16)a1.w;
                af2[ct] = h;
            }
        }
        #pragma unroll
        for (int nt = 0; nt < 4; ++nt) {
            const f16x8 bf = *(const f16x8*)(s_H + ((oc * 4 + nt) * 64 + L) * 8);
            #pragma unroll
            for (int ct = 0; ct < 2; ++ct)
                oacc[ct][nt] = __builtin_amdgcn_mfma_f32_16x16x32_f16(af2[ct], bf, oacc[ct][nt], 0, 0, 0);
        }
    }

    // epilogue: bias + relu + store
    {
        f32x4 bb2[2];
        #pragma unroll
        for (int ct = 0; ct < 2; ++ct)
            bb2[ct] = *(const f32x4*)(b2v + w * 32 + ct * 16 + quad * 4);
        #pragma unroll
        for (int ct = 0; ct < 2; ++ct)
            #pragma unroll
            for (int nt = 0; nt < 4; ++nt) {
                float* op = out + ((size_t)b * H2c + w * 32 + ct * 16 + quad * 4) * NPTS
                                + n0 + nt * 16 + l16;
                #pragma unroll
                for (int j = 0; j < 4; ++j)
                    op[(size_t)j * NPTS] = fmaxf(oacc[ct][nt][j] + bb2[ct][j], 0.f);
            }
    }
}

extern "C" void kernel_launch(void* const* d_in, const int* in_sizes, int n_in,
                              void* d_out, int out_size, void* d_ws, size_t ws_size,
                              hipStream_t stream) {
    (void)in_sizes; (void)n_in; (void)out_size;
    const float* xyz1 = (const float*)d_in[0];
    const float* xyz2 = (const float*)d_in[1];
    const float* p1   = (const float*)d_in[2];
    const float* p2   = (const float*)d_in[3];
    const float* W1   = (const float*)d_in[4];
    const float* b1   = (const float*)d_in[5];
    const float* W2   = (const float*)d_in[6];
    const float* b2   = (const float*)d_in[7];
    float* out = (float*)d_out;

    dim3 grid(BBATCH * (NPTS / TN));   // 1024 blocks = exactly 4/CU resident
    dim3 block(256);
    if (ws_size >= (size_t)WS_F16_TOTAL * 2) {
        _Float16* ws = (_Float16*)d_ws;
        const int nswz = NFRAG_P2 + NFRAG_W1 + NFRAG_W2;   // 540672 = 2112 * 256
        cvt_swz<<<dim3(nswz / 256), dim3(256), 0, stream>>>(p2, W1, W2, ws);
        fp_mfma8<true><<<grid, block, 0, stream>>>(xyz1, xyz2, p1, p2, W1, b1, W2, b2,
                                                   ws + WS_P2S, ws + WS_W1S, ws + WS_W2S, out);
    } else {
        fp_mfma8<false><<<grid, block, 0, stream>>>(xyz1, xyz2, p1, p2, W1, b1, W2, b2,
                                                    nullptr, nullptr, nullptr, out);
    }
}

// Round 2
// 162.871 us; speedup vs baseline: 1.1438x; 1.1438x over previous
//
#include <hip/hip_runtime.h>
#include <math.h>

// Problem constants (from reference setup_inputs)
#define BBATCH 16
#define NPTS   4096
#define MPTS   1024
#define C1c    128
#define C2c    256
#define CINc   384
#define H1c    256
#define H2c    128
#define TN     64

typedef _Float16 f16x8 __attribute__((ext_vector_type(8)));
typedef _Float16 f16x4 __attribute__((ext_vector_type(4)));
typedef float    f32x4 __attribute__((ext_vector_type(4)));

// ---- LDS layout (bytes) ---------------------------------------------------
// phase A: inv dbuf 2 x [4 cc][4 nt][64 lane][8 f16] = 32768 B at offset 0
//          s_xyz2 [1024][3] f32 = 12288 B at 32768 (dies after last gen)
// phase B: s_X frags [12 kc][4 nt][64][8] f16 = 49152 B at 0 (full K=384)
//          (p1 half kq 0..3 overlays inv buf0; interp kq 4..11 overlays
//           buf1 + xyz2 — both dead by then)
// phase C: s_H frags [8 oc][4 nt][64][8] f16 = 32768 B at 0
// s_red: 256 f32 at 49152 (recip overlaid in first 64)
// Total 50176 B -> 3 blocks/CU; regs are the residency limiter (by design:
// launch_bounds(256,3) = 168-reg budget, no spill — R8's (256,4) spilled
// +20 MB scratch writes and cost +12 us).
#define INV_HALF   8192            // f16 elems per inv buffer (16384 B)
#define OFF_XYZ2   32768
#define OFF_RED    49152
#define SMEM_BYTES 50176

// ---- fragment-swizzled workspace layout (f16 elements), unchanged ----
//   p2s: frag ((b*32+s)*16 + wt)*64 + lane : (c=wt*16+(lane&15), m=s*32+(lane>>4)*8+i)
//   W1s: frag (wt*12 + kc)*64 + lane       : (o=wt*16+(lane&15), k=kc*32+(lane>>4)*8+i)
//   W2s: frag (wt2*8 + oc)*64 + lane       : (o=wt2*16+(lane&15), k=oc*32+(lane>>4)*8+i)
#define NFRAG_P2  (BBATCH * 32 * 16 * 64)        // 524288
#define NFRAG_W1  (16 * 12 * 64)                 // 12288
#define NFRAG_W2  (8 * 8 * 64)                   // 4096
#define WS_P2S  0
#define WS_W1S  (NFRAG_P2 * 8)                   // 4194304
#define WS_W2S  (WS_W1S + NFRAG_W1 * 8)
#define WS_F16_TOTAL (WS_W2S + NFRAG_W2 * 8)     // 4325376 f16 = 8650752 B

// ---------------------------------------------------------------------------
// pre-pass: convert + swizzle p2 / W1 / W2 into fragment-contiguous f16
__global__ __launch_bounds__(256) void cvt_swz(
    const float* __restrict__ p2, const float* __restrict__ W1,
    const float* __restrict__ W2, _Float16* __restrict__ ws)
{
    const int t = blockIdx.x * 256 + threadIdx.x;   // one fragment (8 f16) per thread
    const float* src;
    _Float16* dst;
    if (t < NFRAG_P2) {
        const int lane = t & 63, wt = (t >> 6) & 15, s = (t >> 10) & 31, b = t >> 15;
        const int c = wt * 16 + (lane & 15);
        const int m = s * 32 + (lane >> 4) * 8;
        src = p2 + ((size_t)(b * C2c + c)) * MPTS + m;
        dst = ws + WS_P2S + (size_t)t * 8;
    } else if (t < NFRAG_P2 + NFRAG_W1) {
        const int u = t - NFRAG_P2;
        const int lane = u & 63, kc = (u >> 6) % 12, wt = (u >> 6) / 12;
        const int o = wt * 16 + (lane & 15);
        const int k = kc * 32 + (lane >> 4) * 8;
        src = W1 + (size_t)o * CINc + k;
        dst = ws + WS_W1S + (size_t)u * 8;
    } else {
        const int v = t - NFRAG_P2 - NFRAG_W1;
        const int lane = v & 63, oc = (v >> 6) & 7, wt2 = v >> 9;
        const int o = wt2 * 16 + (lane & 15);
        const int k = oc * 32 + (lane >> 4) * 8;
        src = W2 + (size_t)o * H1c + k;
        dst = ws + WS_W2S + (size_t)v * 8;
    }
    const float4 a0 = *(const float4*)(src);
    const float4 a1 = *(const float4*)(src + 4);
    f16x8 h;
    h[0] = (_Float16)a0.x; h[1] = (_Float16)a0.y; h[2] = (_Float16)a0.z; h[3] = (_Float16)a0.w;
    h[4] = (_Float16)a1.x; h[5] = (_Float16)a1.y; h[6] = (_Float16)a1.z; h[7] = (_Float16)a1.w;
    *(f16x8*)dst = h;
}

// ---------------------------------------------------------------------------
// R9: consolidation. Frag-contiguous LDS everywhere (R8, conflicts 3.9M->0.5M)
// + no-spill register regime (R7's (256,3); R8's (256,4) spilled 20 MB) +
// low-latency LDS paths for xyz2 (staged, broadcast ds_read) and p1 (staged
// once as frags BEFORE phase B, not gathered 4x-redundantly inside it) +
// s_setprio around MFMA clusters (independent blocks -> attn-like regime).
template <bool F16P>
__global__ __launch_bounds__(256, 3) void fp_mfma9(
    const float* __restrict__ xyz1, const float* __restrict__ xyz2,
    const float* __restrict__ p1,   const float* __restrict__ p2,
    const float* __restrict__ W1,   const float* __restrict__ b1v,
    const float* __restrict__ W2,   const float* __restrict__ b2v,
    const _Float16* __restrict__ p2s, const _Float16* __restrict__ W1s,
    const _Float16* __restrict__ W2s,
    float* __restrict__ out)
{
    __shared__ __align__(16) char smem[SMEM_BYTES];
    _Float16* s_inv  = (_Float16*)smem;
    float*    s_xyz2 = (float*)(smem + OFF_XYZ2);
    _Float16* s_X    = (_Float16*)smem;
    _Float16* s_H    = (_Float16*)smem;
    float*    s_red  = (float*)(smem + OFF_RED);

    const int tid  = threadIdx.x;
    const int w    = tid >> 6;    // wave 0..3
    const int L    = tid & 63;
    const int quad = L >> 4;
    const int l16  = L & 15;

    // XCD swizzle: each XCD sees 2 batches -> p2s working set (1 MB) L2-resident
    const int id = blockIdx.x;
    const int b  = (id & 7) * 2 + ((id >> 3) & 1);
    const int n0 = (id >> 4) * TN;

    const float* __restrict__ z2b = xyz2 + (size_t)b * MPTS * 3;
    const float* __restrict__ p2b = p2   + (size_t)b * C2c * MPTS;
    const _Float16* __restrict__ p2sb =
        F16P ? (p2s + (((size_t)b * 32 * 16 + (size_t)w * 4) * 64 + L) * 8) : (const _Float16*)nullptr;

    // stage xyz2 (12 KB, coalesced f32x4)
    for (int i = tid; i < MPTS * 3 / 4; i += 256)
        ((f32x4*)s_xyz2)[i] = ((const f32x4*)z2b)[i];

    const float x1x = xyz1[((size_t)b * NPTS + n0 + L) * 3 + 0];
    const float x1y = xyz1[((size_t)b * NPTS + n0 + L) * 3 + 1];
    const float x1z = xyz1[((size_t)b * NPTS + n0 + L) * 3 + 2];

    f32x4 acc[4][4];   // [ct][nt]: row c = w*64+ct*16+quad*4+r, col n = nt*16+l16
    #pragma unroll
    for (int ct = 0; ct < 4; ++ct)
        #pragma unroll
        for (int nt = 0; nt < 4; ++nt)
            acc[ct][nt] = (f32x4){0.f, 0.f, 0.f, 0.f};

    float ssum = 0.f;
    f16x8 Aa[2][4];    // A-frag register dbuf, parity = chunk index & 1

    auto loadA = [&](int s, f16x8 dst[4]) {
        if (F16P) {
            const _Float16* ap = p2sb + (size_t)s * (16 * 64 * 8);
            #pragma unroll
            for (int ct = 0; ct < 4; ++ct)
                dst[ct] = *(const f16x8*)(ap + (size_t)ct * (64 * 8));
        } else {
            const float* ap = p2b + (size_t)(w * 64 + l16) * MPTS + s * 32 + quad * 8;
            #pragma unroll
            for (int ct = 0; ct < 4; ++ct) {
                const float4 a0 = *(const float4*)(ap + (size_t)ct * (16 * MPTS));
                const float4 a1 = *(const float4*)(ap + (size_t)ct * (16 * MPTS) + 4);
                f16x8 h;
                h[0] = (_Float16)a0.x; h[1] = (_Float16)a0.y; h[2] = (_Float16)a0.z; h[3] = (_Float16)a0.w;
                h[4] = (_Float16)a1.x; h[5] = (_Float16)a1.y; h[6] = (_Float16)a1.z; h[7] = (_Float16)a1.w;
                dst[ct] = h;
            }
        }
    };

    // generate the 128-m super-chunk ss into frag-layout buffer (ss&1).
    // thread (w,L): n=L, m = ss*128 + w*32 + g*8 + i  ->  frag (cc=w, nt=quad),
    // lane slot l' = 16*g + l16, elems j=i. One dense f16x8 store per g.
    // xyz2 from LDS: wave-uniform address -> conflict-free broadcast ds_read.
    auto gen = [&](int ss_) {
        _Float16* buf = s_inv + (ss_ & 1) * INV_HALF;
        const float* zbase = s_xyz2 + (size_t)(ss_ * 128 + w * 32) * 3;
        #pragma unroll
        for (int g = 0; g < 4; ++g) {
            const float* zp = zbase + g * 24;
            f32x4 zr[6];
            #pragma unroll
            for (int j = 0; j < 6; ++j) zr[j] = ((const f32x4*)zp)[j];
            const float* zv = (const float*)zr;
            f16x8 iv;
            #pragma unroll
            for (int i = 0; i < 8; ++i) {
                const float dx = x1x - zv[3 * i + 0];
                const float dy = x1y - zv[3 * i + 1];
                const float dz = x1z - zv[3 * i + 2];
                const float d2 = fmaf(dx, dx, fmaf(dy, dy, fmaf(dz, dz, 1e-12f)));
                const float inv = __builtin_amdgcn_rsqf(d2);
                ssum += inv;
                iv[i] = (_Float16)inv;
            }
            *(f16x8*)(buf + (((w * 4 + quad) * 64) + g * 16 + l16) * 8) = iv;
        }
    };

    loadA(0, Aa[0]);
    __syncthreads();   // xyz2 staged
    gen(0);
    __syncthreads();   // super-chunk 0 visible

    for (int ss = 0; ss < 8; ++ss) {
        if (ss + 1 < 8) gen(ss + 1);   // fills other buffer; overlaps inner MFMAs
        const _Float16* buf = s_inv + (ss & 1) * INV_HALF;
        #pragma unroll
        for (int cc = 0; cc < 4; ++cc) {
            const int s = ss * 4 + cc;
            if (s + 1 < 32) loadA(s + 1, Aa[(cc + 1) & 1]);   // barrier-free prefetch
            __builtin_amdgcn_s_setprio(1);
            #pragma unroll
            for (int nt = 0; nt < 4; ++nt) {
                const f16x8 bf = *(const f16x8*)(buf + ((cc * 4 + nt) * 64 + L) * 8);
                #pragma unroll
                for (int ct = 0; ct < 4; ++ct)
                    acc[ct][nt] = __builtin_amdgcn_mfma_f32_16x16x32_f16(Aa[cc & 1][ct], bf, acc[ct][nt], 0, 0, 0);
            }
            __builtin_amdgcn_s_setprio(0);
        }
        __syncthreads();   // reads of buf(ss) done; writes of buf(ss+1) done
    }

    // p1 -> s_X frags kq=w (bytes [0,16K) = dead inv buf0). Issued BEFORE the
    // reduction so the 32 global loads' latency hides under reduction+interp.
    // thread (w,L), frag (kq=w, nt=cc): k = w*32 + quad*8 + j, n = cc*16 + l16.
    {
        const float* p1b = p1 + ((size_t)b * C1c + w * 32 + quad * 8) * NPTS + n0 + l16;
        #pragma unroll
        for (int cc = 0; cc < 4; ++cc) {
            float t[8];
            #pragma unroll
            for (int j = 0; j < 8; ++j) t[j] = p1b[(size_t)j * NPTS + cc * 16];
            f16x8 v;
            #pragma unroll
            for (int j = 0; j < 8; ++j) v[j] = (_Float16)t[j];
            *(f16x8*)(s_X + ((w * 4 + cc) * 64 + L) * 8) = v;
        }
    }

    // ---- S[n] reduction over the 4 m-slice partials; recip overlaid in s_red
    s_red[tid] = ssum;
    __syncthreads();
    if (tid < 64)
        s_red[tid] = 1.0f / (s_red[tid] + s_red[tid + 64] + s_red[tid + 128] + s_red[tid + 192]);
    __syncthreads();   // recip ready; phase-A scratch dead -> interp overlay safe

    // interp -> s_X frags kq = 4 + 2w + (ct>>1) (bytes [16K,48K) = dead buf1+xyz2)
    //   value (n = nt*16+l16, c = w*64+ct*16+quad*4+r):
    //   lane slot = l16 + 16*((ct&1)*2 + (quad>>1)), elem offset (quad&1)*4 + r.
    {
        float rn4[4];
        #pragma unroll
        for (int nt = 0; nt < 4; ++nt) rn4[nt] = s_red[nt * 16 + l16];
        #pragma unroll
        for (int ct = 0; ct < 4; ++ct) {
            const int kq = 4 + 2 * w + (ct >> 1);
            const int lp = l16 + 16 * (((ct & 1) * 2) + (quad >> 1));
            const int jo = (quad & 1) * 4;
            #pragma unroll
            for (int nt = 0; nt < 4; ++nt) {
                const f32x4 v = acc[ct][nt];
                const float r = rn4[nt];
                f16x4 hv;
                hv[0] = (_Float16)(v[0] * r);
                hv[1] = (_Float16)(v[1] * r);
                hv[2] = (_Float16)(v[2] * r);
                hv[3] = (_Float16)(v[3] * r);
                *(f16x4*)(s_X + ((kq * 4 + nt) * 64 + lp) * 8 + jo) = hv;
            }
        }
    }
    __syncthreads();   // full X (p1 + interp) frags complete

    // ---------------- Phase B: h = relu(W1 @ X + b1), K=384 ----------------
    f32x4 hacc[4][4];
    #pragma unroll
    for (int ct = 0; ct < 4; ++ct)
        #pragma unroll
        for (int nt = 0; nt < 4; ++nt)
            hacc[ct][nt] = (f32x4){0.f, 0.f, 0.f, 0.f};

    #pragma unroll 2
    for (int kc = 0; kc < 12; ++kc) {
        f16x8 af[4];
        if (F16P) {
            const _Float16* wp = W1s + (((size_t)(w * 4) * 12 + kc) * 64 + L) * 8;
            #pragma unroll
            for (int ct = 0; ct < 4; ++ct)
                af[ct] = *(const f16x8*)(wp + (size_t)ct * (12 * 64 * 8));
        } else {
            const float* wp = W1 + (size_t)(w * 64 + l16) * CINc + kc * 32 + quad * 8;
            #pragma unroll
            for (int ct = 0; ct < 4; ++ct) {
                const float4 a0 = *(const float4*)(wp + ct * (16 * CINc));
                const float4 a1 = *(const float4*)(wp + ct * (16 * CINc) + 4);
                f16x8 h;
                h[0] = (_Float16)a0.x; h[1] = (_Float16)a0.y; h[2] = (_Float16)a0.z; h[3] = (_Float16)a0.w;
                h[4] = (_Float16)a1.x; h[5] = (_Float16)a1.y; h[6] = (_Float16)a1.z; h[7] = (_Float16)a1.w;
                af[ct] = h;
            }
        }
        __builtin_amdgcn_s_setprio(1);
        #pragma unroll
        for (int nt = 0; nt < 4; ++nt) {
            const f16x8 bf = *(const f16x8*)(s_X + ((kc * 4 + nt) * 64 + L) * 8);
            #pragma unroll
            for (int ct = 0; ct < 4; ++ct)
                hacc[ct][nt] = __builtin_amdgcn_mfma_f32_16x16x32_f16(af[ct], bf, hacc[ct][nt], 0, 0, 0);
        }
        __builtin_amdgcn_s_setprio(0);
    }

    __syncthreads();   // all s_X reads done before overlaying s_H

    // bias + relu + stage h -> s_H frag layout (same mapping, oq = 2w + (ct>>1))
    {
        f32x4 bb[4];
        #pragma unroll
        for (int ct = 0; ct < 4; ++ct)
            bb[ct] = *(const f32x4*)(b1v + w * 64 + ct * 16 + quad * 4);
        #pragma unroll
        for (int ct = 0; ct < 4; ++ct) {
            const int oq = 2 * w + (ct >> 1);
            const int lp = l16 + 16 * (((ct & 1) * 2) + (quad >> 1));
            const int jo = (quad & 1) * 4;
            #pragma unroll
            for (int nt = 0; nt < 4; ++nt) {
                const f32x4 v = hacc[ct][nt];
                f16x4 hv;
                hv[0] = (_Float16)fmaxf(v[0] + bb[ct][0], 0.f);
                hv[1] = (_Float16)fmaxf(v[1] + bb[ct][1], 0.f);
                hv[2] = (_Float16)fmaxf(v[2] + bb[ct][2], 0.f);
                hv[3] = (_Float16)fmaxf(v[3] + bb[ct][3], 0.f);
                *(f16x4*)(s_H + ((oq * 4 + nt) * 64 + lp) * 8 + jo) = hv;
            }
        }
    }
    __syncthreads();

    // ---------------- Phase C: out = relu(W2 @ h + b2), K=256 --------------
    f32x4 oacc[2][4];
    #pragma unroll
    for (int ct = 0; ct < 2; ++ct)
        #pragma unroll
        for (int nt = 0; nt < 4; ++nt)
            oacc[ct][nt] = (f32x4){0.f, 0.f, 0.f, 0.f};

    #pragma unroll 2
    for (int oc = 0; oc < 8; ++oc) {
        f16x8 af2[2];
        if (F16P) {
            const _Float16* wp = W2s + (((size_t)(w * 2) * 8 + oc) * 64 + L) * 8;
            #pragma unroll
            for (int ct = 0; ct < 2; ++ct)
                af2[ct] = *(const f16x8*)(wp + (size_t)ct * (8 * 64 * 8));
        } else {
            const float* wp = W2 + (size_t)(w * 32 + l16) * H1c + oc * 32 + quad * 8;
            #pragma unroll
            for (int ct = 0; ct < 2; ++ct) {
                const float4 a0 = *(const float4*)(wp + ct * (16 * H1c));
                const float4 a1 = *(const float4*)(wp + ct * (16 * H1c) + 4);
                f16x8 h;
                h[0] = (_Float16)a0.x; h[1] = (_Float16)a0.y; h[2] = (_Float16)a0.z; h[3] = (_Float16)a0.w;
                h[4] = (_Float16)a1.x; h[5] = (_Float16)a1.y; h[6] = (_Float16)a1.z; h[7] = (_Float16)a1.w;
                af2[ct] = h;
            }
        }
        __builtin_amdgcn_s_setprio(1);
        #pragma unroll
        for (int nt = 0; nt < 4; ++nt) {
            const f16x8 bf = *(const f16x8*)(s_H + ((oc * 4 + nt) * 64 + L) * 8);
            #pragma unroll
            for (int ct = 0; ct < 2; ++ct)
                oacc[ct][nt] = __builtin_amdgcn_mfma_f32_16x16x32_f16(af2[ct], bf, oacc[ct][nt], 0, 0, 0);
        }
        __builtin_amdgcn_s_setprio(0);
    }

    // epilogue: bias + relu + store
    {
        f32x4 bb2[2];
        #pragma unroll
        for (int ct = 0; ct < 2; ++ct)
            bb2[ct] = *(const f32x4*)(b2v + w * 32 + ct * 16 + quad * 4);
        #pragma unroll
        for (int ct = 0; ct < 2; ++ct)
            #pragma unroll
            for (int nt = 0; nt < 4; ++nt) {
                float* op = out + ((size_t)b * H2c + w * 32 + ct * 16 + quad * 4) * NPTS
                                + n0 + nt * 16 + l16;
                #pragma unroll
                for (int j = 0; j < 4; ++j)
                    op[(size_t)j * NPTS] = fmaxf(oacc[ct][nt][j] + bb2[ct][j], 0.f);
            }
    }
}

extern "C" void kernel_launch(void* const* d_in, const int* in_sizes, int n_in,
                              void* d_out, int out_size, void* d_ws, size_t ws_size,
                              hipStream_t stream) {
    (void)in_sizes; (void)n_in; (void)out_size;
    const float* xyz1 = (const float*)d_in[0];
    const float* xyz2 = (const float*)d_in[1];
    const float* p1   = (const float*)d_in[2];
    const float* p2   = (const float*)d_in[3];
    const float* W1   = (const float*)d_in[4];
    const float* b1   = (const float*)d_in[5];
    const float* W2   = (const float*)d_in[6];
    const float* b2   = (const float*)d_in[7];
    float* out = (float*)d_out;

    dim3 grid(BBATCH * (NPTS / TN));   // 1024 blocks
    dim3 block(256);
    if (ws_size >= (size_t)WS_F16_TOTAL * 2) {
        _Float16* ws = (_Float16*)d_ws;
        const int nswz = NFRAG_P2 + NFRAG_W1 + NFRAG_W2;   // 540672 = 2112 * 256
        cvt_swz<<<dim3(nswz / 256), dim3(256), 0, stream>>>(p2, W1, W2, ws);
        fp_mfma9<true><<<grid, block, 0, stream>>>(xyz1, xyz2, p1, p2, W1, b1, W2, b2,
                                                   ws + WS_P2S, ws + WS_W1S, ws + WS_W2S, out);
    } else {
        fp_mfma9<false><<<grid, block, 0, stream>>>(xyz1, xyz2, p1, p2, W1, b1, W2, b2,
                                                    nullptr, nullptr, nullptr, out);
    }
}